// Round 13
// baseline (209.313 us; speedup 1.0000x reference)
//
#include <hip/hip_runtime.h>
#include <hip/hip_bf16.h>
#include <stdint.h>

#define NN 40000
#define NE 640000
#define NB 157                      // ceil(NN/256)
#define SUB8 ((size_t)(NN + 1) * 64)  // bytes per fp8 column sub-table

typedef __attribute__((ext_vector_type(8))) short bf16x8;
typedef __attribute__((ext_vector_type(4))) float f32x4;
typedef __attribute__((ext_vector_type(2))) float f32x2v;
typedef __attribute__((ext_vector_type(4))) unsigned u32x4;

static __device__ __forceinline__ unsigned short f2b(float f) {
    unsigned b = __float_as_uint(f);
    return (unsigned short)((b + 0x7FFFu + ((b >> 16) & 1u)) >> 16);
}
static __device__ __forceinline__ float blo(unsigned v) { return __uint_as_float(v << 16); }
static __device__ __forceinline__ float bhi(unsigned v) { return __uint_as_float(v & 0xffff0000u); }

static __device__ __forceinline__ void acc8(float* a, uint4 v) {
    a[0] += blo(v.x); a[1] += bhi(v.x);
    a[2] += blo(v.y); a[3] += bhi(v.y);
    a[4] += blo(v.z); a[5] += bhi(v.z);
    a[6] += blo(v.w); a[7] += bhi(v.w);
}
static __device__ __forceinline__ void acc4(float* a, uint2 v) {
    a[0] += blo(v.x); a[1] += bhi(v.x);
    a[2] += blo(v.y); a[3] += bhi(v.y);
}

// ---------------- fp8 e4m3 encode/decode (HW cvt if available) ----------------

#if __has_builtin(__builtin_amdgcn_cvt_pk_fp8_f32) && __has_builtin(__builtin_amdgcn_cvt_pk_f32_fp8)
#define FP8_HW 1
#else
#define FP8_HW 0
#endif

static __device__ __forceinline__ unsigned char f2fp8_sw(float f) {
    f = fminf(fmaxf(f, -448.f), 448.f);
    unsigned b = __float_as_uint(f);
    unsigned s = (b >> 24) & 0x80u;
    unsigned ab = b & 0x7fffffffu;
    if (ab < 0x3c000000u) return (unsigned char)s;
    unsigned r = ab + 0x7ffffu + ((ab >> 20) & 1u);
    unsigned e = ((r >> 23) - 120u) & 0xfu;
    unsigned m = (r >> 20) & 7u;
    return (unsigned char)(s | (e << 3) | m);
}
static __device__ __forceinline__ float fp82f_sw(unsigned char u) {
    unsigned s = ((unsigned)u & 0x80u) << 24;
    unsigned e = (u >> 3) & 15u, m = u & 7u;
    float nrm = __uint_as_float(s | ((e + 120u) << 23) | (m << 20));
    float dnm = __uint_as_float(s | 0x3f800000u) * (float)m * 0.001953125f;
    return e ? nrm : dnm;
}

static __device__ __forceinline__ unsigned pack_fp8x4(float a, float b, float c, float d) {
#if FP8_HW
    int v = __builtin_amdgcn_cvt_pk_fp8_f32(a, b, 0, false);
    v = __builtin_amdgcn_cvt_pk_fp8_f32(c, d, v, true);
    return (unsigned)v;
#else
    return (unsigned)f2fp8_sw(a) | ((unsigned)f2fp8_sw(b) << 8) |
           ((unsigned)f2fp8_sw(c) << 16) | ((unsigned)f2fp8_sw(d) << 24);
#endif
}
static __device__ __forceinline__ unsigned char f2fp8(float v) {
#if FP8_HW
    return (unsigned char)(__builtin_amdgcn_cvt_pk_fp8_f32(v, v, 0, false) & 0xff);
#else
    return f2fp8_sw(v);
#endif
}

static __device__ __forceinline__ void acc4f8(float* a, unsigned v) {
#if FP8_HW
    f32x2v p0 = __builtin_amdgcn_cvt_pk_f32_fp8((int)v, false);
    f32x2v p1 = __builtin_amdgcn_cvt_pk_f32_fp8((int)v, true);
    a[0] += p0.x; a[1] += p0.y; a[2] += p1.x; a[3] += p1.y;
#else
    a[0] += fp82f_sw(v & 0xff);         a[1] += fp82f_sw((v >> 8) & 0xff);
    a[2] += fp82f_sw((v >> 16) & 0xff); a[3] += fp82f_sw(v >> 24);
#endif
}
static __device__ __forceinline__ void acc16f8(float* a, uint4 v) {
    acc4f8(a, v.x); acc4f8(a + 4, v.y); acc4f8(a + 8, v.z); acc4f8(a + 12, v.w);
}

// ---------------- CSR build ----------------

__global__ __launch_bounds__(256) void scan1_kernel(const int* __restrict__ deg,
                                                    int* __restrict__ bsum) {
    int i = blockIdx.x * 256 + threadIdx.x;
    int v = (i < NN) ? deg[i] : 0;
#pragma unroll
    for (int off = 1; off < 64; off <<= 1) v += __shfl_xor(v, off);
    __shared__ int ws4[4];
    if ((threadIdx.x & 63) == 0) ws4[threadIdx.x >> 6] = v;
    __syncthreads();
    if (threadIdx.x == 0) bsum[blockIdx.x] = ws4[0] + ws4[1] + ws4[2] + ws4[3];
}

// per-block scan; block base computed inline from bsum (scan_top folded in)
__global__ __launch_bounds__(256) void scan2_kernel(const int* __restrict__ deg,
                                                    const int* __restrict__ bsum,
                                                    int* __restrict__ row_ptr) {
    int b = blockIdx.x;
    int tid = threadIdx.x, lane = tid & 63, wv = tid >> 6;
    __shared__ int base_s;
    __shared__ int wsum[4];
    if (tid < 64) {
        int s = 0;
        for (int idx = tid; idx < b; idx += 64) s += bsum[idx];
#pragma unroll
        for (int off = 1; off < 64; off <<= 1) s += __shfl_xor(s, off);
        if (tid == 0) base_s = s;
    }
    int i = b * 256 + tid;
    int v = (i < NN) ? deg[i] : 0;
    int s = v;
#pragma unroll
    for (int off = 1; off < 64; off <<= 1) { int t = __shfl_up(s, off); if (lane >= off) s += t; }
    if (lane == 63) wsum[wv] = s;
    __syncthreads();
    int add = base_s;
    for (int w = 0; w < wv; ++w) add += wsum[w];
    if (i < NN) row_ptr[i] = add + s - v;
    if (i == NN - 1) row_ptr[NN] = add + s;
}

__global__ void fill_csr_kernel(const int* __restrict__ src, const int* __restrict__ dst,
                                const int* __restrict__ row_ptr, int* __restrict__ cursor,
                                int* __restrict__ csr, int n) {
    int i = blockIdx.x * blockDim.x + threadIdx.x;
    if (i < n) {
        int d = dst[i];
        int pos = row_ptr[d] + atomicAdd(&cursor[d], 1);
        csr[pos] = src[i];
    }
}

// ---------------- fused prep: count deg + cast x (bf16 + split fp8) + weights + pads ----

__global__ __launch_bounds__(256) void prep_kernel(
    const float* __restrict__ x, const int* __restrict__ dst,
    const float* __restrict__ Ws0, const float* __restrict__ Wn0,
    const float* __restrict__ Ws1, const float* __restrict__ Wn1,
    const float* __restrict__ Ws2, const float* __restrict__ Wn2,
    int* __restrict__ deg, unsigned short* __restrict__ X,
    unsigned char* __restrict__ X8, unsigned char* __restrict__ H18,
    unsigned short* __restrict__ HnA, unsigned short* __restrict__ HnB,
    unsigned short* __restrict__ Wt0, unsigned short* __restrict__ Wt1,
    unsigned short* __restrict__ Wt2s, unsigned short* __restrict__ Wt2n) {
    int b = blockIdx.x, tid = threadIdx.x;
    if (b < 2500) {
        int i = b * 256 + tid;
        atomicAdd(&deg[dst[i]], 1);
    } else if (b < 7500) {
        int i = (b - 2500) * 256 + tid;   // one per 4 elems of x
        int e = i << 2;
        int node = e >> 7, col = e & 127;
        float4 v = *(const float4*)(x + e);
        uint2 o;
        o.x = f2b(v.x) | ((unsigned)f2b(v.y) << 16);
        o.y = f2b(v.z) | ((unsigned)f2b(v.w) << 16);
        *(uint2*)(X + e) = o;
        int c = col >> 6, co = col & 63;
        *(unsigned*)(X8 + (size_t)c * SUB8 + (size_t)node * 64 + co) =
            pack_fp8x4(v.x, v.y, v.z, v.w);
    } else if (b < 7804) {
        int i = (b - 7500) * 256 + tid;
        if (i < 65536) {
            int l = i >> 15, j = i & 32767;
            int n = j >> 8, k = j & 255;
            const float* Ws = l ? Ws1 : Ws0;
            const float* Wn = l ? Wn1 : Wn0;
            float v = (k < 128) ? Ws[k * 128 + n] : Wn[(k - 128) * 128 + n];
            (l ? Wt1 : Wt0)[n * 256 + k] = f2b(v);
        } else if (i < 65536 + 6144) {
            int j = i - 65536;                  // Wt2s: [48 n][128 k]
            int n = j >> 7, k = j & 127;
            float v = (n < 47) ? Ws2[k * 47 + n] : 0.f;
            Wt2s[n * 128 + k] = f2b(v);
        } else {
            int j = i - 65536 - 6144;           // Wt2n: [48 n][128 k]
            int n = j >> 7, k = j & 127;
            float v = (n < 47) ? Wn2[k * 47 + n] : 0.f;
            Wt2n[n * 128 + k] = f2b(v);
        }
    } else {
        // zero pad-rows (gather padding targets), row NN of each table
        if (tid < 8)       *(uint2*)(X8 + (size_t)NN * 64 + tid * 8) = (uint2){0, 0};
        else if (tid < 16) *(uint2*)(X8 + SUB8 + (size_t)NN * 64 + (tid - 8) * 8) = (uint2){0, 0};
        else if (tid < 24) *(uint2*)(H18 + (size_t)NN * 64 + (tid - 16) * 8) = (uint2){0, 0};
        else if (tid < 32) *(uint2*)(H18 + SUB8 + (size_t)NN * 64 + (tid - 24) * 8) = (uint2){0, 0};
        else if (tid < 40) *(uint2*)((unsigned char*)(HnA + (size_t)NN * 32) + (tid - 32) * 8) = (uint2){0, 0};
        else if (tid < 44) *(uint2*)((unsigned char*)(HnB + (size_t)NN * 16) + (tid - 40) * 8) = (uint2){0, 0};
    }
}

// ---------------- gather pass: fp8 sub-table (64B rows, L2-resident) -> agg half ----------------
// 16 nodes/block, 16 groups x 4 lanes, quarter-lists, 4-deep bursts (64 lines in flight/wave).
// csr nt-loaded, agg nt-stored: only the gather table occupies L2.

__global__ __launch_bounds__(256) void agg8_kernel(
    const unsigned char* __restrict__ T, const int* __restrict__ csr,
    const int* __restrict__ row_ptr, unsigned short* __restrict__ agg, int col0) {
    int tid = threadIdx.x;
    int wv = tid >> 6, lane = tid & 63;
    int lr4 = lane & 3, g = lane >> 2;
    int t = g >> 2, q = g & 3;
    int nb = blockIdx.x * 16 + wv * 4;

    int rp5 = (lane < 5) ? row_ptr[nb + lane] : 0;
    int beg = __shfl(rp5, t), end = __shfl(rp5, t + 1);
    int deg = end - beg;
    int qlen = (deg + 3) >> 2;
    int js = beg + q * qlen;
    int je = min(js + qlen, end);
    int last = (je > js) ? je - 1 : js;

    float a[16] = {};
    for (int j = js; j < je; j += 4) {
        int idxs[4];
#pragma unroll
        for (int k = 0; k < 4; ++k) idxs[k] = __builtin_nontemporal_load(csr + min(j + k, last));
#pragma unroll
        for (int k = 0; k < 4; ++k)
            if (j + k >= je) idxs[k] = NN;
        uint4 v[4];
#pragma unroll
        for (int k = 0; k < 4; ++k)
            v[k] = *(const uint4*)(T + (size_t)idxs[k] * 64 + lr4 * 16);
#pragma unroll
        for (int k = 0; k < 4; ++k) acc16f8(a, v[k]);
    }
    // merge 4 quarter-groups (lane bits 2,3)
#pragma unroll
    for (int k = 0; k < 16; ++k) {
        a[k] += __shfl_xor(a[k], 4);
        a[k] += __shfl_xor(a[k], 8);
    }
    if (q == 0) {
        float inv = 1.0f / fmaxf((float)deg, 1.0f);
        u32x4 o0, o1;
        o0.x = f2b(a[0] * inv)  | ((unsigned)f2b(a[1] * inv) << 16);
        o0.y = f2b(a[2] * inv)  | ((unsigned)f2b(a[3] * inv) << 16);
        o0.z = f2b(a[4] * inv)  | ((unsigned)f2b(a[5] * inv) << 16);
        o0.w = f2b(a[6] * inv)  | ((unsigned)f2b(a[7] * inv) << 16);
        o1.x = f2b(a[8] * inv)  | ((unsigned)f2b(a[9] * inv) << 16);
        o1.y = f2b(a[10] * inv) | ((unsigned)f2b(a[11] * inv) << 16);
        o1.z = f2b(a[12] * inv) | ((unsigned)f2b(a[13] * inv) << 16);
        o1.w = f2b(a[14] * inv) | ((unsigned)f2b(a[15] * inv) << 16);
        int node = nb + t;
        u32x4* dstp = (u32x4*)(agg + (size_t)node * 128 + col0 + lr4 * 16);
        __builtin_nontemporal_store(o0, dstp);
        __builtin_nontemporal_store(o1, dstp + 1);
    }
}

// ---------------- layer GEMM: out = relu([Hin | agg] @ Wt + b); B in registers ----------------

template <bool RELU, bool WFP8>
__global__ __launch_bounds__(256) void gemm_layer_kernel(
    const unsigned short* __restrict__ Hin, const unsigned short* __restrict__ agg,
    const unsigned short* __restrict__ Wt, const float* __restrict__ bias,
    unsigned short* __restrict__ Hout, unsigned char* __restrict__ H8out, int tpb) {
    int wv = threadIdx.x >> 6, lane = threadIdx.x & 63;
    int lr = lane & 15, lg = lane >> 4;

    bf16x8 bfr[2][8];
    float bs[2];
#pragma unroll
    for (int c = 0; c < 2; ++c) {
        int n = (wv * 2 + c) * 16 + lr;
#pragma unroll
        for (int kt = 0; kt < 8; ++kt)
            bfr[c][kt] = *(const bf16x8*)(Wt + (size_t)n * 256 + kt * 32 + lg * 8);
        bs[c] = bias[n];
    }

    for (int tt = 0; tt < tpb; ++tt) {
        int m0 = (blockIdx.x * tpb + tt) * 16;
        bf16x8 afr[8];
#pragma unroll
        for (int kt = 0; kt < 4; ++kt)
            afr[kt] = __builtin_nontemporal_load(
                (const bf16x8*)(Hin + (size_t)(m0 + lr) * 128 + kt * 32 + lg * 8));
#pragma unroll
        for (int kt = 0; kt < 4; ++kt)
            afr[4 + kt] = __builtin_nontemporal_load(
                (const bf16x8*)(agg + (size_t)(m0 + lr) * 128 + kt * 32 + lg * 8));
        f32x4 acc0 = (f32x4){0.f, 0.f, 0.f, 0.f};
        f32x4 acc1 = (f32x4){0.f, 0.f, 0.f, 0.f};
#pragma unroll
        for (int kt = 0; kt < 8; ++kt) {
            acc0 = __builtin_amdgcn_mfma_f32_16x16x32_bf16(afr[kt], bfr[0][kt], acc0, 0, 0, 0);
            acc1 = __builtin_amdgcn_mfma_f32_16x16x32_bf16(afr[kt], bfr[1][kt], acc1, 0, 0, 0);
        }
        int n0 = (wv * 2) * 16 + lr;
        int n1 = n0 + 16;
        int sub = wv >> 1;   // n0,n1 in same 64-col half
#pragma unroll
        for (int r = 0; r < 4; ++r) {
            int m = m0 + lg * 4 + r;
            float v0 = acc0[r] + bs[0];
            float v1 = acc1[r] + bs[1];
            if (RELU) { v0 = fmaxf(v0, 0.f); v1 = fmaxf(v1, 0.f); }
            Hout[(size_t)m * 128 + n0] = f2b(v0);
            Hout[(size_t)m * 128 + n1] = f2b(v1);
            if (WFP8) {
                unsigned char* hb = H8out + (size_t)sub * SUB8 + (size_t)m * 64;
                hb[n0 & 63] = f2fp8(v0);
                hb[n1 & 63] = f2fp8(v1);
            }
        }
    }
}

// ---------------- layer-2 dual GEMM: out(self+bias) fp32 and HnA/HnB = h2@Wn2 (split bf16) ----

__global__ __launch_bounds__(192) void dual_gemm_kernel(
    const unsigned short* __restrict__ H2,
    const unsigned short* __restrict__ Wt2s, const unsigned short* __restrict__ Wt2n,
    const float* __restrict__ b2, float* __restrict__ out,
    unsigned short* __restrict__ HnA, unsigned short* __restrict__ HnB) {
    int wv = threadIdx.x >> 6, lane = threadIdx.x & 63;
    int lr = lane & 15, lg = lane >> 4;

    bf16x8 bfr[2][4];
    float bs[2];
#pragma unroll
    for (int c = 0; c < 2; ++c) {
        int t = wv * 2 + c;
        bool is_s = t < 3;
        int n = (is_s ? t : t - 3) * 16 + lr;
        const unsigned short* W = is_s ? Wt2s : Wt2n;
#pragma unroll
        for (int kt = 0; kt < 4; ++kt)
            bfr[c][kt] = *(const bf16x8*)(W + (size_t)n * 128 + kt * 32 + lg * 8);
        bs[c] = (is_s && n < 47) ? b2[n] : 0.f;
    }

    for (int tt = 0; tt < 2; ++tt) {
        int m0 = blockIdx.x * 32 + tt * 16;
        bf16x8 afr[4];
#pragma unroll
        for (int kt = 0; kt < 4; ++kt)
            afr[kt] = __builtin_nontemporal_load(
                (const bf16x8*)(H2 + (size_t)(m0 + lr) * 128 + kt * 32 + lg * 8));
        f32x4 acc[2];
#pragma unroll
        for (int c = 0; c < 2; ++c) acc[c] = (f32x4){0.f, 0.f, 0.f, 0.f};
#pragma unroll
        for (int kt = 0; kt < 4; ++kt)
#pragma unroll
            for (int c = 0; c < 2; ++c)
                acc[c] = __builtin_amdgcn_mfma_f32_16x16x32_bf16(afr[kt], bfr[c][kt], acc[c], 0, 0, 0);
#pragma unroll
        for (int c = 0; c < 2; ++c) {
            int t = wv * 2 + c;
            bool is_s = t < 3;
            int n = (is_s ? t : t - 3) * 16 + lr;
#pragma unroll
            for (int r = 0; r < 4; ++r) {
                int m = m0 + lg * 4 + r;
                float v = acc[c][r] + bs[c];
                if (is_s) {
                    if (n < 47) out[(size_t)m * 47 + n] = v;
                } else {
                    if (n < 32) HnA[(size_t)m * 32 + n] = f2b(v);
                    else        HnB[(size_t)m * 16 + (n - 32)] = f2b(v);
                }
            }
        }
    }
}

// ---------------- layer-2 aggout passes: bf16 sub-tables, += mean into out ----------------
// pass A: HnA [NN+1][32] (cols 0-31), uint4/lane; pass B: HnB [NN+1][16] (cols 32-46), uint2/lane.

__global__ __launch_bounds__(256) void aggoutA_kernel(
    const unsigned short* __restrict__ T, const int* __restrict__ csr,
    const int* __restrict__ row_ptr, float* __restrict__ out) {
    int tid = threadIdx.x;
    int wv = tid >> 6, lane = tid & 63;
    int lr4 = lane & 3, g = lane >> 2;
    int t = g >> 2, q = g & 3;
    int nb = blockIdx.x * 16 + wv * 4;
    int rp5 = (lane < 5) ? row_ptr[nb + lane] : 0;
    int beg = __shfl(rp5, t), end = __shfl(rp5, t + 1);
    int deg = end - beg;
    int qlen = (deg + 3) >> 2;
    int js = beg + q * qlen;
    int je = min(js + qlen, end);
    int last = (je > js) ? je - 1 : js;

    float a[8] = {};
    for (int j = js; j < je; j += 4) {
        int idxs[4];
#pragma unroll
        for (int k = 0; k < 4; ++k) idxs[k] = __builtin_nontemporal_load(csr + min(j + k, last));
#pragma unroll
        for (int k = 0; k < 4; ++k)
            if (j + k >= je) idxs[k] = NN;
        uint4 v[4];
#pragma unroll
        for (int k = 0; k < 4; ++k)
            v[k] = *(const uint4*)(T + (size_t)idxs[k] * 32 + lr4 * 8);
#pragma unroll
        for (int k = 0; k < 4; ++k) acc8(a, v[k]);
    }
#pragma unroll
    for (int k = 0; k < 8; ++k) {
        a[k] += __shfl_xor(a[k], 4);
        a[k] += __shfl_xor(a[k], 8);
    }
    if (q == 0) {
        float inv = 1.0f / fmaxf((float)deg, 1.0f);
        int node = nb + t;
#pragma unroll
        for (int r = 0; r < 8; ++r)
            out[(size_t)node * 47 + lr4 * 8 + r] += a[r] * inv;
    }
}

__global__ __launch_bounds__(256) void aggoutB_kernel(
    const unsigned short* __restrict__ T, const int* __restrict__ csr,
    const int* __restrict__ row_ptr, float* __restrict__ out) {
    int tid = threadIdx.x;
    int wv = tid >> 6, lane = tid & 63;
    int lr4 = lane & 3, g = lane >> 2;
    int t = g >> 2, q = g & 3;
    int nb = blockIdx.x * 16 + wv * 4;
    int rp5 = (lane < 5) ? row_ptr[nb + lane] : 0;
    int beg = __shfl(rp5, t), end = __shfl(rp5, t + 1);
    int deg = end - beg;
    int qlen = (deg + 3) >> 2;
    int js = beg + q * qlen;
    int je = min(js + qlen, end);
    int last = (je > js) ? je - 1 : js;

    float a[4] = {};
    for (int j = js; j < je; j += 4) {
        int idxs[4];
#pragma unroll
        for (int k = 0; k < 4; ++k) idxs[k] = __builtin_nontemporal_load(csr + min(j + k, last));
#pragma unroll
        for (int k = 0; k < 4; ++k)
            if (j + k >= je) idxs[k] = NN;
        uint2 v[4];
#pragma unroll
        for (int k = 0; k < 4; ++k)
            v[k] = *(const uint2*)(T + (size_t)idxs[k] * 16 + lr4 * 4);
#pragma unroll
        for (int k = 0; k < 4; ++k) acc4(a, v[k]);
    }
#pragma unroll
    for (int k = 0; k < 4; ++k) {
        a[k] += __shfl_xor(a[k], 4);
        a[k] += __shfl_xor(a[k], 8);
    }
    if (q == 0) {
        float inv = 1.0f / fmaxf((float)deg, 1.0f);
        int node = nb + t;
#pragma unroll
        for (int r = 0; r < 4; ++r) {
            int col = 32 + lr4 * 4 + r;
            if (col < 47) out[(size_t)node * 47 + col] += a[r] * inv;
        }
    }
}

// ---------------- launch ----------------

extern "C" void kernel_launch(void* const* d_in, const int* in_sizes, int n_in,
                              void* d_out, int out_size, void* d_ws, size_t ws_size,
                              hipStream_t stream) {
    const float* x   = (const float*)d_in[0];
    const int*   src = (const int*)d_in[1];
    const int*   dst = (const int*)d_in[2];
    const float* Ws0 = (const float*)d_in[3];
    const float* Wn0 = (const float*)d_in[4];
    const float* b0  = (const float*)d_in[5];
    const float* Ws1 = (const float*)d_in[6];
    const float* Wn1 = (const float*)d_in[7];
    const float* b1  = (const float*)d_in[8];
    const float* Ws2 = (const float*)d_in[9];
    const float* Wn2 = (const float*)d_in[10];
    const float* b2  = (const float*)d_in[11];
    float* out = (float*)d_out;

    uintptr_t p = ((uintptr_t)d_ws + 255) & ~(uintptr_t)255;
    auto take = [&](size_t bytes) {
        void* r = (void*)p;
        p = (p + bytes + 255) & ~(uintptr_t)255;
        return r;
    };
    int* deg     = (int*)take(40000 * 4);
    int* cursor  = (int*)take(40000 * 4);
    int* row_ptr = (int*)take(40004 * 4);
    int* csr     = (int*)take(640000 * 4);
    unsigned short* X   = (unsigned short*)take((size_t)NN * 128 * 2);
    unsigned short* H1  = (unsigned short*)take((size_t)NN * 128 * 2);
    unsigned short* H2  = X;   // alias: X dead after layer 0
    unsigned short* agg = (unsigned short*)take((size_t)NN * 128 * 2);
    unsigned short* Wt0 = (unsigned short*)take(128 * 256 * 2);
    unsigned short* Wt1 = (unsigned short*)take(128 * 256 * 2);
    unsigned short* Wt2s = (unsigned short*)take(48 * 128 * 2);
    unsigned short* Wt2n = (unsigned short*)take(48 * 128 * 2);
    unsigned short* HnA = (unsigned short*)take((size_t)(NN + 1) * 32 * 2);
    unsigned short* HnB = (unsigned short*)take((size_t)(NN + 1) * 16 * 2);
    int* bsum = (int*)take(NB * 4);
    unsigned char* X8  = (unsigned char*)take(2 * SUB8);
    unsigned char* H18 = (unsigned char*)take(2 * SUB8);

    (void)hipMemsetAsync(deg, 0, 80000 * sizeof(int), stream);   // deg + cursor
    prep_kernel<<<7805, 256, 0, stream>>>(x, dst, Ws0, Wn0, Ws1, Wn1, Ws2, Wn2,
                                          deg, X, X8, H18, HnA, HnB, Wt0, Wt1, Wt2s, Wt2n);
    scan1_kernel<<<NB, 256, 0, stream>>>(deg, bsum);
    scan2_kernel<<<NB, 256, 0, stream>>>(deg, bsum, row_ptr);
    fill_csr_kernel<<<2500, 256, 0, stream>>>(src, dst, row_ptr, cursor, csr, NE);

    // layer 0
    agg8_kernel<<<2500, 256, 0, stream>>>(X8, csr, row_ptr, agg, 0);
    agg8_kernel<<<2500, 256, 0, stream>>>(X8 + SUB8, csr, row_ptr, agg, 64);
    gemm_layer_kernel<true, true><<<1250, 256, 0, stream>>>(X, agg, Wt0, b0, H1, H18, 2);
    // layer 1
    agg8_kernel<<<2500, 256, 0, stream>>>(H18, csr, row_ptr, agg, 0);
    agg8_kernel<<<2500, 256, 0, stream>>>(H18 + SUB8, csr, row_ptr, agg, 64);
    gemm_layer_kernel<true, false><<<1250, 256, 0, stream>>>(H1, agg, Wt1, b1, H2, nullptr, 2);
    // layer 2
    dual_gemm_kernel<<<1250, 192, 0, stream>>>(H2, Wt2s, Wt2n, b2, out, HnA, HnB);
    aggoutA_kernel<<<2500, 256, 0, stream>>>(HnA, csr, row_ptr, out);
    aggoutB_kernel<<<2500, 256, 0, stream>>>(HnB, csr, row_ptr, out);
}

// Round 14
// 178.709 us; speedup vs baseline: 1.1713x; 1.1713x over previous
//
#include <hip/hip_runtime.h>
#include <hip/hip_bf16.h>
#include <stdint.h>

#define NN 40000
#define NE 640000
#define NB 157   // ceil(NN/256)

typedef __attribute__((ext_vector_type(8))) short bf16x8;
typedef __attribute__((ext_vector_type(4))) float f32x4;
typedef __attribute__((ext_vector_type(2))) float f32x2v;

static __device__ __forceinline__ unsigned short f2b(float f) {
    unsigned b = __float_as_uint(f);
    return (unsigned short)((b + 0x7FFFu + ((b >> 16) & 1u)) >> 16);
}
static __device__ __forceinline__ float blo(unsigned v) { return __uint_as_float(v << 16); }
static __device__ __forceinline__ float bhi(unsigned v) { return __uint_as_float(v & 0xffff0000u); }

static __device__ __forceinline__ void acc4(float* a, uint2 v) {
    a[0] += blo(v.x); a[1] += bhi(v.x);
    a[2] += blo(v.y); a[3] += bhi(v.y);
}

// ---------------- fp8 e4m3 encode/decode (HW cvt if available) ----------------

#if __has_builtin(__builtin_amdgcn_cvt_pk_fp8_f32) && __has_builtin(__builtin_amdgcn_cvt_pk_f32_fp8)
#define FP8_HW 1
#else
#define FP8_HW 0
#endif

static __device__ __forceinline__ unsigned char f2fp8_sw(float f) {
    f = fminf(fmaxf(f, -448.f), 448.f);
    unsigned b = __float_as_uint(f);
    unsigned s = (b >> 24) & 0x80u;
    unsigned ab = b & 0x7fffffffu;
    if (ab < 0x3c000000u) return (unsigned char)s;       // |f| < 2^-7 -> 0 (FTZ)
    unsigned r = ab + 0x7ffffu + ((ab >> 20) & 1u);      // RTN-even at 3-bit mantissa
    unsigned e = ((r >> 23) - 120u) & 0xfu;
    unsigned m = (r >> 20) & 7u;
    return (unsigned char)(s | (e << 3) | m);
}
static __device__ __forceinline__ float fp82f_sw(unsigned char u) {
    unsigned s = ((unsigned)u & 0x80u) << 24;
    unsigned e = (u >> 3) & 15u, m = u & 7u;
    float nrm = __uint_as_float(s | ((e + 120u) << 23) | (m << 20));
    float dnm = __uint_as_float(s | 0x3f800000u) * (float)m * 0.001953125f;
    return e ? nrm : dnm;
}

static __device__ __forceinline__ unsigned pack_fp8x4(float a, float b, float c, float d) {
#if FP8_HW
    int v = __builtin_amdgcn_cvt_pk_fp8_f32(a, b, 0, false);
    v = __builtin_amdgcn_cvt_pk_fp8_f32(c, d, v, true);
    return (unsigned)v;
#else
    return (unsigned)f2fp8_sw(a) | ((unsigned)f2fp8_sw(b) << 8) |
           ((unsigned)f2fp8_sw(c) << 16) | ((unsigned)f2fp8_sw(d) << 24);
#endif
}

// accumulate 4 fp8 (one uint) into a[0..3]
static __device__ __forceinline__ void acc4f8(float* a, unsigned v) {
#if FP8_HW
    f32x2v p0 = __builtin_amdgcn_cvt_pk_f32_fp8((int)v, false);
    f32x2v p1 = __builtin_amdgcn_cvt_pk_f32_fp8((int)v, true);
    a[0] += p0.x; a[1] += p0.y; a[2] += p1.x; a[3] += p1.y;
#else
    a[0] += fp82f_sw(v & 0xff);         a[1] += fp82f_sw((v >> 8) & 0xff);
    a[2] += fp82f_sw((v >> 16) & 0xff); a[3] += fp82f_sw(v >> 24);
#endif
}
// accumulate 16 fp8 (one uint4) into a[0..15]
static __device__ __forceinline__ void acc16f8(float* a, uint4 v) {
    acc4f8(a, v.x); acc4f8(a + 4, v.y); acc4f8(a + 8, v.z); acc4f8(a + 12, v.w);
}

// ---------------- CSR build ----------------

__global__ __launch_bounds__(256) void scan1_kernel(const int* __restrict__ deg,
                                                    int* __restrict__ bsum) {
    int i = blockIdx.x * 256 + threadIdx.x;
    int v = (i < NN) ? deg[i] : 0;
#pragma unroll
    for (int off = 1; off < 64; off <<= 1) v += __shfl_xor(v, off);
    __shared__ int ws4[4];
    if ((threadIdx.x & 63) == 0) ws4[threadIdx.x >> 6] = v;
    __syncthreads();
    if (threadIdx.x == 0) bsum[blockIdx.x] = ws4[0] + ws4[1] + ws4[2] + ws4[3];
}

__global__ void scan_top_kernel(const int* __restrict__ bsum, int* __restrict__ btop) {
    int lane = threadIdx.x;
    int run = 0;
    for (int base = 0; base < NB; base += 64) {
        int idx = base + lane;
        int v = (idx < NB) ? bsum[idx] : 0;
        int s = v;
#pragma unroll
        for (int off = 1; off < 64; off <<= 1) { int t = __shfl_up(s, off); if (lane >= off) s += t; }
        if (idx < NB) btop[idx] = run + s - v;
        run += __shfl(s, 63);
    }
}

__global__ __launch_bounds__(256) void scan2_kernel(const int* __restrict__ deg,
                                                    const int* __restrict__ btop,
                                                    int* __restrict__ row_ptr) {
    int b = blockIdx.x;
    int i = b * 256 + threadIdx.x;
    int lane = threadIdx.x & 63, wv = threadIdx.x >> 6;
    int v = (i < NN) ? deg[i] : 0;
    int s = v;
#pragma unroll
    for (int off = 1; off < 64; off <<= 1) { int t = __shfl_up(s, off); if (lane >= off) s += t; }
    __shared__ int wsum[4];
    if (lane == 63) wsum[wv] = s;
    __syncthreads();
    int add = btop[b];
    for (int w = 0; w < wv; ++w) add += wsum[w];
    if (i < NN) row_ptr[i] = add + s - v;
    if (i == NN - 1) row_ptr[NN] = add + s;
}

__global__ void fill_csr_kernel(const int* __restrict__ src, const int* __restrict__ dst,
                                const int* __restrict__ row_ptr, int* __restrict__ cursor,
                                int* __restrict__ csr, int n) {
    int i = blockIdx.x * blockDim.x + threadIdx.x;
    if (i < n) {
        int d = dst[i];
        int pos = row_ptr[d] + atomicAdd(&cursor[d], 1);
        csr[pos] = src[i];
    }
}

// ---------------- fused prep: count deg + cast x (bf16 + fp8) + build weights + pads ----
// deg/cursor zeroed by hipMemsetAsync before this kernel.

__global__ __launch_bounds__(256) void prep_kernel(
    const float* __restrict__ x, const int* __restrict__ dst,
    const float* __restrict__ Ws0, const float* __restrict__ Wn0,
    const float* __restrict__ Ws1, const float* __restrict__ Wn1,
    const float* __restrict__ Ws2, const float* __restrict__ Wn2,
    int* __restrict__ deg, unsigned short* __restrict__ X,
    unsigned char* __restrict__ X8, unsigned char* __restrict__ H18,
    unsigned short* __restrict__ Hn,
    unsigned short* __restrict__ Wt0, unsigned short* __restrict__ Wt1,
    unsigned short* __restrict__ Wt2s, unsigned short* __restrict__ Wt2n) {
    int b = blockIdx.x, tid = threadIdx.x;
    if (b < 2500) {
        int i = b * 256 + tid;
        atomicAdd(&deg[dst[i]], 1);
    } else if (b < 7500) {
        int i = (b - 2500) * 256 + tid;   // one per 4 elems of x
        int e = i << 2;
        float4 v = *(const float4*)(x + e);
        uint2 o;
        o.x = f2b(v.x) | ((unsigned)f2b(v.y) << 16);
        o.y = f2b(v.z) | ((unsigned)f2b(v.w) << 16);
        *(uint2*)(X + e) = o;
        *(unsigned*)(X8 + e) = pack_fp8x4(v.x, v.y, v.z, v.w);
    } else if (b < 7804) {
        int i = (b - 7500) * 256 + tid;
        if (i < 65536) {
            // Wt0/Wt1: [128 n][256 k], k<128 = Ws rows, k>=128 = Wn rows
            int l = i >> 15, j = i & 32767;
            int n = j >> 8, k = j & 255;
            const float* Ws = l ? Ws1 : Ws0;
            const float* Wn = l ? Wn1 : Wn0;
            float v = (k < 128) ? Ws[k * 128 + n] : Wn[(k - 128) * 128 + n];
            (l ? Wt1 : Wt0)[n * 256 + k] = f2b(v);
        } else if (i < 65536 + 6144) {
            int j = i - 65536;                  // Wt2s: [48 n][128 k]
            int n = j >> 7, k = j & 127;
            float v = (n < 47) ? Ws2[k * 47 + n] : 0.f;
            Wt2s[n * 128 + k] = f2b(v);
        } else {
            int j = i - 65536 - 6144;           // Wt2n: [48 n][128 k]
            int n = j >> 7, k = j & 127;
            float v = (n < 47) ? Wn2[k * 47 + n] : 0.f;
            Wt2n[n * 128 + k] = f2b(v);
        }
    } else {
        // zero pad-rows (gather padding targets)
        if (tid < 16) *(uint2*)(X8 + (size_t)NN * 128 + tid * 8) = (uint2){0, 0};
        else if (tid < 32) *(uint2*)(H18 + (size_t)NN * 128 + (tid - 16) * 8) = (uint2){0, 0};
        else if (tid < 48) *(uint2*)((unsigned char*)(Hn + (size_t)NN * 64) + (tid - 32) * 8) = (uint2){0, 0};
    }
}

// ---------------- fused SAGE layer: 16 nodes/block, concurrent fp8 gather->LDS, MFMA ----------------
// Hin: bf16 [NN][128] (self path). H8in: fp8 [NN+1][128], 128B rows, row NN = zeros (pad).
// 256 threads / 4 waves. Per wave: 8 groups of 8 lanes; groups 2t,2t+1 own node nb+t's
// edge-list halves -> 4 nodes gathered CONCURRENTLY with 8-DEEP bursts (typ. one burst
// covers the whole half; 64 indep lines in flight/wave). Out-of-range slots read the
// zero row (no masks). One shfl_xor(8) merges the halves. Self A-fragments issued
// BEFORE the gather so their latency hides under it.

template <bool RELU, bool WFP8>
__global__ __launch_bounds__(256) void sage_layer_kernel(
    const unsigned short* __restrict__ Hin, const unsigned char* __restrict__ H8in,
    const int* __restrict__ csr, const int* __restrict__ row_ptr,
    const unsigned short* __restrict__ Wt, const float* __restrict__ bias,
    unsigned short* __restrict__ Hout, unsigned char* __restrict__ H8out) {
    // [16 rows][16 chunks of 16B], chunk XOR-swizzled by row to kill bank conflicts
    __shared__ unsigned short agg_lds[16 * 128];

    int tid = threadIdx.x;
    int wv = tid >> 6, lane = tid & 63;
    int lr = lane & 15, lg = lane >> 4;     // phase-2 roles
    int lr8 = lane & 7, g = lane >> 3;      // gather roles: 8 groups x 8 lanes
    int t = g >> 1, sub = g & 1;            // node-slot and half
    int m0 = blockIdx.x * 16;

    // issue self-path A fragments early (latency hides under gather)
    bf16x8 afr[8];
#pragma unroll
    for (int kt = 0; kt < 4; ++kt)
        afr[kt] = *(const bf16x8*)(Hin + (size_t)(m0 + lr) * 128 + kt * 32 + lg * 8);

    // phase 1: all 4 nodes concurrently; 8-deep bursts over each node's half-list
    int nb = m0 + wv * 4;
    int rp5 = (lane < 5) ? row_ptr[nb + lane] : 0;
    int beg = __shfl(rp5, t), end = __shfl(rp5, t + 1);
    int deg = end - beg;
    int half = (deg + 1) >> 1;
    int js = beg + sub * half;
    int je = sub ? end : beg + half;
    int last = (je > js) ? je - 1 : js;

    float a[16] = {};
    for (int j = js; j < je; j += 8) {
        int idxs[8];
#pragma unroll
        for (int k = 0; k < 8; ++k) idxs[k] = csr[min(j + k, last)];
#pragma unroll
        for (int k = 0; k < 8; ++k)
            if (j + k >= je) idxs[k] = NN;
        uint4 v[8];
#pragma unroll
        for (int k = 0; k < 8; ++k)
            v[k] = *(const uint4*)(H8in + (size_t)idxs[k] * 128 + lr8 * 16);
#pragma unroll
        for (int k = 0; k < 8; ++k) acc16f8(a, v[k]);
    }
    // merge the two halves of each node (groups 2t <-> 2t+1 differ in lane bit 3)
#pragma unroll
    for (int k = 0; k < 16; ++k) a[k] += __shfl_xor(a[k], 8);

    if (sub == 0) {
        float inv = 1.0f / fmaxf((float)deg, 1.0f);
        uint4 o0, o1;
        o0.x = f2b(a[0] * inv)  | ((unsigned)f2b(a[1] * inv) << 16);
        o0.y = f2b(a[2] * inv)  | ((unsigned)f2b(a[3] * inv) << 16);
        o0.z = f2b(a[4] * inv)  | ((unsigned)f2b(a[5] * inv) << 16);
        o0.w = f2b(a[6] * inv)  | ((unsigned)f2b(a[7] * inv) << 16);
        o1.x = f2b(a[8] * inv)  | ((unsigned)f2b(a[9] * inv) << 16);
        o1.y = f2b(a[10] * inv) | ((unsigned)f2b(a[11] * inv) << 16);
        o1.z = f2b(a[12] * inv) | ((unsigned)f2b(a[13] * inv) << 16);
        o1.w = f2b(a[14] * inv) | ((unsigned)f2b(a[15] * inv) << 16);
        int row = wv * 4 + t;
        *(uint4*)&agg_lds[row * 128 + ((2 * lr8) ^ row) * 8] = o0;
        *(uint4*)&agg_lds[row * 128 + ((2 * lr8 + 1) ^ row) * 8] = o1;
    }
    __syncthreads();

    // phase 2: one 16-row M-tile; A = self + neigh(LDS); B streamed from L2
#pragma unroll
    for (int kt = 0; kt < 4; ++kt) {
        int chunk = (kt * 4 + lg) ^ lr;             // matching swizzle (row = lr)
        afr[4 + kt] = *(const bf16x8*)&agg_lds[lr * 128 + chunk * 8];
    }

    int n0 = (wv * 2) * 16 + lr;
    int n1 = n0 + 16;
    f32x4 acc0 = (f32x4){0.f, 0.f, 0.f, 0.f};
    f32x4 acc1 = (f32x4){0.f, 0.f, 0.f, 0.f};
#pragma unroll
    for (int kt = 0; kt < 8; ++kt) {
        bf16x8 b0 = *(const bf16x8*)(Wt + (size_t)n0 * 256 + kt * 32 + lg * 8);
        bf16x8 b1 = *(const bf16x8*)(Wt + (size_t)n1 * 256 + kt * 32 + lg * 8);
        acc0 = __builtin_amdgcn_mfma_f32_16x16x32_bf16(afr[kt], b0, acc0, 0, 0, 0);
        acc1 = __builtin_amdgcn_mfma_f32_16x16x32_bf16(afr[kt], b1, acc1, 0, 0, 0);
    }

    float bs0 = bias[n0], bs1 = bias[n1];
#pragma unroll
    for (int r = 0; r < 4; ++r) {
        int m = m0 + lg * 4 + r;
        float v0 = acc0[r] + bs0;
        float v1 = acc1[r] + bs1;
        if (RELU) { v0 = fmaxf(v0, 0.f); v1 = fmaxf(v1, 0.f); }
        Hout[(size_t)m * 128 + n0] = f2b(v0);
        Hout[(size_t)m * 128 + n1] = f2b(v1);
        if (WFP8) {
#if FP8_HW
            H8out[(size_t)m * 128 + n0] =
                (unsigned char)(__builtin_amdgcn_cvt_pk_fp8_f32(v0, v0, 0, false) & 0xff);
            H8out[(size_t)m * 128 + n1] =
                (unsigned char)(__builtin_amdgcn_cvt_pk_fp8_f32(v1, v1, 0, false) & 0xff);
#else
            H8out[(size_t)m * 128 + n0] = f2fp8_sw(v0);
            H8out[(size_t)m * 128 + n1] = f2fp8_sw(v1);
#endif
        }
    }
}

// ---------------- layer-2 dual GEMM: one read of h2 -> out(self+bias) and Hn = h2@Wn2 ----------------
// Hn stride 64 shorts = 128B line-aligned rows; row NN is a zero pad (set in prep).

__global__ __launch_bounds__(192) void dual_gemm_kernel(
    const unsigned short* __restrict__ H2,
    const unsigned short* __restrict__ Wt2s, const unsigned short* __restrict__ Wt2n,
    const float* __restrict__ b2,
    float* __restrict__ out, unsigned short* __restrict__ Hn) {
    int wv = threadIdx.x >> 6, lane = threadIdx.x & 63;
    int lr = lane & 15, lg = lane >> 4;

    bf16x8 bfr[2][4];
    float bs[2];
#pragma unroll
    for (int c = 0; c < 2; ++c) {
        int t = wv * 2 + c;
        bool is_s = t < 3;
        int n = (is_s ? t : t - 3) * 16 + lr;
        const unsigned short* W = is_s ? Wt2s : Wt2n;
#pragma unroll
        for (int kt = 0; kt < 4; ++kt)
            bfr[c][kt] = *(const bf16x8*)(W + (size_t)n * 128 + kt * 32 + lg * 8);
        bs[c] = (is_s && n < 47) ? b2[n] : 0.f;
    }

    for (int tt = 0; tt < 2; ++tt) {
        int m0 = blockIdx.x * 32 + tt * 16;
        bf16x8 afr[4];
#pragma unroll
        for (int kt = 0; kt < 4; ++kt)
            afr[kt] = *(const bf16x8*)(H2 + (size_t)(m0 + lr) * 128 + kt * 32 + lg * 8);
        f32x4 acc[2];
#pragma unroll
        for (int c = 0; c < 2; ++c) acc[c] = (f32x4){0.f, 0.f, 0.f, 0.f};
#pragma unroll
        for (int kt = 0; kt < 4; ++kt)
#pragma unroll
            for (int c = 0; c < 2; ++c)
                acc[c] = __builtin_amdgcn_mfma_f32_16x16x32_bf16(afr[kt], bfr[c][kt], acc[c], 0, 0, 0);
#pragma unroll
        for (int c = 0; c < 2; ++c) {
            int t = wv * 2 + c;
            bool is_s = t < 3;
            int n = (is_s ? t : t - 3) * 16 + lr;
#pragma unroll
            for (int r = 0; r < 4; ++r) {
                int m = m0 + lg * 4 + r;
                float v = acc[c][r] + bs[c];
                if (is_s) {
                    if (n < 47) out[(size_t)m * 47 + n] = v;
                } else {
                    Hn[(size_t)m * 64 + n] = f2b(v);   // cols>=47 are 0 (zeroed weights)
                }
            }
        }
    }
}

// ---------------- layer-2 neighbor mean in 47-col space, += into out ----------------
// 2 nodes/wave, 2 half-groups x 16 lanes per node, 8-deep bursts, zero-row padding.

__global__ __launch_bounds__(256) void aggregate_out_kernel(
    const unsigned short* __restrict__ Hn, const int* __restrict__ csr,
    const int* __restrict__ row_ptr, float* __restrict__ out) {
    int wave = (blockIdx.x * blockDim.x + threadIdx.x) >> 6;
    int lane = threadIdx.x & 63;
    int nb = wave * 2;
    if (nb >= NN) return;
    int t = lane >> 5, sub = (lane >> 4) & 1, lc = lane & 15;
    int rp3 = (lane < 3) ? row_ptr[nb + lane] : 0;
    int beg = __shfl(rp3, t), end = __shfl(rp3, t + 1);
    int deg = end - beg;
    int half = (deg + 1) >> 1;
    int js = beg + sub * half;
    int je = sub ? end : beg + half;
    int last = (je > js) ? je - 1 : js;

    float a[4] = {};
    for (int j = js; j < je; j += 8) {
        int idxs[8];
#pragma unroll
        for (int k = 0; k < 8; ++k) idxs[k] = csr[min(j + k, last)];
#pragma unroll
        for (int k = 0; k < 8; ++k)
            if (j + k >= je) idxs[k] = NN;
        uint2 v[8];
#pragma unroll
        for (int k = 0; k < 8; ++k)
            v[k] = *(const uint2*)(Hn + (size_t)idxs[k] * 64 + lc * 4);
#pragma unroll
        for (int k = 0; k < 8; ++k) acc4(a, v[k]);
    }
    // merge halves (groups differ in lane bit 4)
#pragma unroll
    for (int k = 0; k < 4; ++k) a[k] += __shfl_xor(a[k], 16);

    if (sub == 0 && lc < 12) {
        float inv = 1.0f / fmaxf((float)deg, 1.0f);
        int node = nb + t;
        int c0 = lc * 4;
#pragma unroll
        for (int r = 0; r < 4; ++r)
            if (c0 + r < 47) out[(size_t)node * 47 + c0 + r] += a[r] * inv;
    }
}

// ---------------- launch ----------------

extern "C" void kernel_launch(void* const* d_in, const int* in_sizes, int n_in,
                              void* d_out, int out_size, void* d_ws, size_t ws_size,
                              hipStream_t stream) {
    const float* x   = (const float*)d_in[0];
    const int*   src = (const int*)d_in[1];
    const int*   dst = (const int*)d_in[2];
    const float* Ws0 = (const float*)d_in[3];
    const float* Wn0 = (const float*)d_in[4];
    const float* b0  = (const float*)d_in[5];
    const float* Ws1 = (const float*)d_in[6];
    const float* Wn1 = (const float*)d_in[7];
    const float* b1  = (const float*)d_in[8];
    const float* Ws2 = (const float*)d_in[9];
    const float* Wn2 = (const float*)d_in[10];
    const float* b2  = (const float*)d_in[11];
    float* out = (float*)d_out;

    // 256-B-aligned workspace carve-out (rows must not straddle cache lines)
    uintptr_t p = ((uintptr_t)d_ws + 255) & ~(uintptr_t)255;
    auto take = [&](size_t bytes) {
        void* r = (void*)p;
        p = (p + bytes + 255) & ~(uintptr_t)255;
        return r;
    };
    int* deg     = (int*)take(40000 * 4);   // contiguous with cursor (multiple of 256)
    int* cursor  = (int*)take(40000 * 4);
    int* row_ptr = (int*)take(40004 * 4);
    int* csr     = (int*)take(640000 * 4);
    unsigned short* X   = (unsigned short*)take((size_t)NN * 128 * 2);
    unsigned short* H1  = (unsigned short*)take((size_t)NN * 128 * 2);
    unsigned short* H2  = X;   // alias: X dead after layer 0
    unsigned short* Wt0 = (unsigned short*)take(128 * 256 * 2);
    unsigned short* Wt1 = (unsigned short*)take(128 * 256 * 2);
    unsigned short* Wt2s = (unsigned short*)take(48 * 128 * 2);
    unsigned short* Wt2n = (unsigned short*)take(48 * 128 * 2);
    unsigned short* Hn  = (unsigned short*)take((size_t)(NN + 1) * 64 * 2);
    int* bsum = (int*)take(NB * 4);
    int* btop = (int*)take(NB * 4);
    unsigned char* X8  = (unsigned char*)take((size_t)(NN + 1) * 128);
    unsigned char* H18 = (unsigned char*)take((size_t)(NN + 1) * 128);

    (void)hipMemsetAsync(deg, 0, 80000 * sizeof(int), stream);   // deg + cursor
    prep_kernel<<<7805, 256, 0, stream>>>(x, dst, Ws0, Wn0, Ws1, Wn1, Ws2, Wn2,
                                          deg, X, X8, H18, Hn, Wt0, Wt1, Wt2s, Wt2n);
    scan1_kernel<<<NB, 256, 0, stream>>>(deg, bsum);
    scan_top_kernel<<<1, 64, 0, stream>>>(bsum, btop);
    scan2_kernel<<<NB, 256, 0, stream>>>(deg, btop, row_ptr);
    fill_csr_kernel<<<2500, 256, 0, stream>>>(src, dst, row_ptr, cursor, csr, NE);

    sage_layer_kernel<true, true><<<2500, 256, 0, stream>>>(X, X8, csr, row_ptr, Wt0, b0, H1, H18);
    sage_layer_kernel<true, false><<<2500, 256, 0, stream>>>(H1, H18, csr, row_ptr, Wt1, b1, H2, nullptr);
    dual_gemm_kernel<<<1250, 192, 0, stream>>>(H2, Wt2s, Wt2n, b2, out, Hn);
    aggregate_out_kernel<<<5000, 256, 0, stream>>>(Hn, csr, row_ptr, out);
}